// Round 5
// baseline (712.380 us; speedup 1.0000x reference)
//
#include <hip/hip_runtime.h>
#include <math.h>

#define TT 65536
#define DD 256
#define EE 8
#define HH 512
#define OO 256

typedef unsigned int u32;
typedef unsigned short u16;
typedef __attribute__((ext_vector_type(4))) float f32x4;
typedef __attribute__((ext_vector_type(16))) float f32x16;
typedef __attribute__((ext_vector_type(2))) u32 u32x2;
typedef __attribute__((ext_vector_type(4))) u32 u32x4;
typedef __attribute__((ext_vector_type(8))) __bf16 bf16x8;

__device__ __forceinline__ u16 f2bf(float f) {
    u32 u = __builtin_bit_cast(u32, f);
    u32 r = (u + 0x7fffu + ((u >> 16) & 1u)) >> 16;
    return (u16)r;
}

__device__ __forceinline__ bf16x8 ld_frag(const void* p) {
    u32x4 v = *(const u32x4*)p;
    return __builtin_bit_cast(bf16x8, v);
}

// tanh-form gelu via exp2 + rcp
__device__ __forceinline__ float gelu_fast(float v) {
    float t = v * v;
    float u = __builtin_fmaf(t, -0.1029479f, -2.3022075f);
    float z = v * u;
    float e = __builtin_amdgcn_exp2f(z);
    return v * __builtin_amdgcn_rcpf(1.0f + e);
}

// ---------------- convert/transpose weights ----------------
__global__ __launch_bounds__(256) void k_conv_w1(const float* __restrict__ w1, u16* __restrict__ w1t) {
    int i = blockIdx.x * 256 + threadIdx.x;            // < E*H*D = 1M
    int d = i & 255, h = (i >> 8) & 511, e = i >> 17;
    w1t[i] = f2bf(w1[((size_t)e << 17) + ((size_t)d << 9) + h]);
}
__global__ __launch_bounds__(256) void k_conv_w2(const float* __restrict__ w2, u16* __restrict__ w2t) {
    int i = blockIdx.x * 256 + threadIdx.x;            // < E*O*H = 1M
    int h = i & 511, o = (i >> 9) & 255, e = i >> 17;
    w2t[i] = f2bf(w2[((size_t)e << 17) + ((size_t)h << 8) + o]);
}

// ---------------- gating ----------------
__global__ __launch_bounds__(256) void k_gating(const float* __restrict__ x,
                                                const float* __restrict__ gw,
                                                const float* __restrict__ gb,
                                                float* __restrict__ wt,
                                                double* __restrict__ part) {
    __shared__ float gws[DD * EE];
    __shared__ float gbs[EE];
    __shared__ double red[256];
    int tid = threadIdx.x;
    for (int i = tid; i < DD * EE; i += 256) gws[i] = gw[i];
    if (tid < EE) gbs[tid] = gb[tid];
    __syncthreads();

    int t = blockIdx.x * 256 + tid;
    double l[EE];
#pragma unroll
    for (int e = 0; e < EE; ++e) l[e] = (double)gbs[e];

    const f32x4* xr = (const f32x4*)(x + (size_t)t * DD);
    for (int d4 = 0; d4 < DD / 4; ++d4) {
        f32x4 xv = xr[d4];
#pragma unroll
        for (int j = 0; j < 4; ++j) {
            double xs = (double)xv[j];
            int d = d4 * 4 + j;
#pragma unroll
            for (int e = 0; e < EE; ++e) l[e] += xs * (double)gws[d * EE + e];
        }
    }
    double mx = l[0];
#pragma unroll
    for (int e = 1; e < EE; ++e) mx = l[e] > mx ? l[e] : mx;
    double p[EE], s = 0.0;
#pragma unroll
    for (int e = 0; e < EE; ++e) { p[e] = exp(l[e] - mx); s += p[e]; }
    double inv = 1.0 / s;
    double ent = 0.0;
#pragma unroll
    for (int e = 0; e < EE; ++e) { p[e] *= inv; ent += p[e] * log(p[e] + 1e-8); }

    bool mask[EE];
#pragma unroll
    for (int e = 0; e < EE; ++e) {
        double c = 0.0; int rk = 0;
#pragma unroll
        for (int f = 0; f < EE; ++f) {
            bool before = (p[f] > p[e]) || (p[f] == p[e] && f < e);
            if (before) { c += p[f]; rk++; }
        }
        c += p[e];
        mask[e] = (c <= 0.7) || (rk == 0);
    }
    double ms = 0.0;
#pragma unroll
    for (int e = 0; e < EE; ++e) if (mask[e]) ms += p[e];
    double inv2 = 1.0 / ms;
#pragma unroll
    for (int e = 0; e < EE; ++e) wt[(size_t)e * TT + t] = (float)(mask[e] ? p[e] * inv2 : 0.0);

    red[tid] = -ent;
    __syncthreads();
    for (int st = 128; st > 0; st >>= 1) {
        if (tid < st) red[tid] += red[tid + st];
        __syncthreads();
    }
    if (tid == 0) part[blockIdx.x] = red[0];
}

__global__ __launch_bounds__(256) void k_final(const double* __restrict__ part, float* __restrict__ loss) {
    __shared__ double red[256];
    int tid = threadIdx.x;
    red[tid] = part[tid];
    __syncthreads();
    for (int st = 128; st > 0; st >>= 1) {
        if (tid < st) red[tid] += red[tid + st];
        __syncthreads();
    }
    if (tid == 0) loss[0] = (float)(red[0] / (double)TT);
}

// ---------------- fused MoE MLP (v5: 128 tok/block, 2:1 MFMA:LDS) ----------------
// 128 tokens/block, 512 threads (8 waves). 16 chunks of 256 h (e = c>>1).
// G1: wave = 64h x 64tok (2x2 tiles): per ks 2 global A + 2 LDS B -> 4 MFMA.
// G2: wave = 64tok x 64o (2x2 tiles): per ks 2 LDS A + 2 global B -> 4 MFMA.
// LDS = 64K Xs + 64K Hs + 4K wts = 132K -> 1 block/CU, 8 waves.
__global__ __launch_bounds__(512, 2) void k_moe(const float* __restrict__ x,
                                                const u16* __restrict__ w1t,
                                                const u16* __restrict__ w2t,
                                                const float* __restrict__ b1,
                                                const float* __restrict__ b2,
                                                const float* __restrict__ wtg,
                                                float* __restrict__ out) {
    __shared__ __align__(16) unsigned char smem[135168];
    unsigned char* Xs = smem;                     // 128 rows x 512B (bf16, swizzled)
    unsigned char* Hs = smem + 65536;             // 128 rows x 512B (bf16, swizzled)
    float* wts = (float*)(smem + 131072);         // [E][128] f32

    const int tid = threadIdx.x;                  // 0..511
    const int wid = tid >> 6;                     // 0..7
    const int lane = tid & 63;
    const int l31 = lane & 31;
    const int lg2 = lane >> 5;                    // 0..1
    const int gm = wid & 1;                       // token-group (64 tokens)
    const int gh = wid >> 1;                      // G1: 64-h strip within 256-chunk
    const int gn = wid >> 1;                      // G2: 64-o strip within 256
    const int t0 = blockIdx.x * 128;

    // stage X tile: f32 -> bf16, swizzle ^((row&15)<<4), rows = 512B
    {
        const f32x4* xsrc = (const f32x4*)(x + (size_t)t0 * DD);
#pragma unroll
        for (int i = 0; i < 8; ++i) {
            int L = i * 8192 + tid * 16;          // byte offset in 128KB bf16 tile
            f32x4 a = xsrc[L >> 3];
            f32x4 b = xsrc[(L >> 3) + 1];
            u32x4 o;
            o.x = (u32)f2bf(a[0]) | ((u32)f2bf(a[1]) << 16);
            o.y = (u32)f2bf(a[2]) | ((u32)f2bf(a[3]) << 16);
            o.z = (u32)f2bf(b[0]) | ((u32)f2bf(b[1]) << 16);
            o.w = (u32)f2bf(b[2]) | ((u32)f2bf(b[3]) << 16);
            int row = L >> 9;
            *(u32x4*)(Xs + (L ^ ((row & 15) << 4))) = o;
        }
    }
    // wts[e][tok]
    {
        int i0 = tid;
        wts[i0] = wtg[(size_t)(i0 >> 7) * TT + t0 + (i0 & 127)];
        int i1 = tid + 512;
        wts[i1] = wtg[(size_t)(i1 >> 7) * TT + t0 + (i1 & 127)];
    }
    __syncthreads();

    f32x16 oacc[2][2];
#pragma unroll
    for (int m = 0; m < 2; ++m)
#pragma unroll
        for (int n = 0; n < 2; ++n) oacc[m][n] = (f32x16)0.0f;

#pragma unroll 1
    for (int c = 0; c < 16; ++c) {
        const int e = c >> 1;
        // ---- G1: hf[m][t], rows h = c*256 + gh*64 + m*32 + crow, cols tok = gm*64 + t*32 + l31
        f32x16 hf[2][2];
#pragma unroll
        for (int m = 0; m < 2; ++m)
#pragma unroll
            for (int t = 0; t < 2; ++t) hf[m][t] = (f32x16)0.0f;

        const u16* w1p = w1t + ((size_t)(c * 256 + gh * 64 + l31)) * DD + lg2 * 8;
#pragma unroll 2
        for (int ks = 0; ks < 16; ++ks) {
            bf16x8 a0 = ld_frag(w1p + ks * 16);
            bf16x8 a1 = ld_frag(w1p + 32 * DD + ks * 16);
            bf16x8 b0, b1f;
            {
                int tok = gm * 64 + l31;
                int byt = tok * 512 + ks * 32 + lg2 * 16;
                b0 = ld_frag(Xs + (byt ^ ((tok & 15) << 4)));
                tok += 32;
                byt += 32 * 512;
                b1f = ld_frag(Xs + (byt ^ ((tok & 15) << 4)));
            }
            hf[0][0] = __builtin_amdgcn_mfma_f32_32x32x16_bf16(a0, b0, hf[0][0], 0, 0, 0);
            hf[0][1] = __builtin_amdgcn_mfma_f32_32x32x16_bf16(a0, b1f, hf[0][1], 0, 0, 0);
            hf[1][0] = __builtin_amdgcn_mfma_f32_32x32x16_bf16(a1, b0, hf[1][0], 0, 0, 0);
            hf[1][1] = __builtin_amdgcn_mfma_f32_32x32x16_bf16(a1, b1f, hf[1][1], 0, 0, 0);
        }
        __syncthreads();               // all waves done reading Hs for G2(c-1)
        // epilogue: +b1, gelu, *wgt, pack -> Hs
#pragma unroll
        for (int m = 0; m < 2; ++m) {
            f32x4 bbv[4];
            const float* b1p = b1 + c * 256 + gh * 64 + m * 32 + lg2 * 4;
#pragma unroll
            for (int q = 0; q < 4; ++q) bbv[q] = *(const f32x4*)(b1p + q * 8);
#pragma unroll
            for (int t = 0; t < 2; ++t) {
                int tok = gm * 64 + t * 32 + l31;
                float wgt = wts[e * 128 + tok];
#pragma unroll
                for (int q = 0; q < 4; ++q) {
                    float g[4];
#pragma unroll
                    for (int r = 0; r < 4; ++r) {
                        float v = hf[m][t][q * 4 + r] + bbv[q][r];
                        g[r] = gelu_fast(v) * wgt;
                    }
                    u32x2 pk;
                    pk.x = (u32)f2bf(g[0]) | ((u32)f2bf(g[1]) << 16);
                    pk.y = (u32)f2bf(g[2]) | ((u32)f2bf(g[3]) << 16);
                    int hl = gh * 64 + m * 32 + q * 8 + lg2 * 4;   // h within chunk [0,256)
                    int byt = tok * 512 + hl * 2;
                    *(u32x2*)(Hs + (byt ^ ((tok & 15) << 4))) = pk;
                }
            }
        }
        __syncthreads();               // Hs(c) ready
        // ---- G2: oacc[m][n] += Hs[tok][k] * W2[k][o]
        const u16* w2p = w2t + ((size_t)(e * OO + gn * 64 + l31)) * HH + (c & 1) * 256 + lg2 * 8;
#pragma unroll 2
        for (int ks = 0; ks < 16; ++ks) {
            bf16x8 A0, A1;
            {
                int tok = gm * 64 + l31;
                int byt = tok * 512 + ks * 32 + lg2 * 16;
                A0 = ld_frag(Hs + (byt ^ ((tok & 15) << 4)));
                tok += 32;
                byt += 32 * 512;
                A1 = ld_frag(Hs + (byt ^ ((tok & 15) << 4)));
            }
            bf16x8 B0 = ld_frag(w2p + ks * 16);
            bf16x8 B1 = ld_frag(w2p + 32 * HH + ks * 16);
            oacc[0][0] = __builtin_amdgcn_mfma_f32_32x32x16_bf16(A0, B0, oacc[0][0], 0, 0, 0);
            oacc[0][1] = __builtin_amdgcn_mfma_f32_32x32x16_bf16(A0, B1, oacc[0][1], 0, 0, 0);
            oacc[1][0] = __builtin_amdgcn_mfma_f32_32x32x16_bf16(A1, B0, oacc[1][0], 0, 0, 0);
            oacc[1][1] = __builtin_amdgcn_mfma_f32_32x32x16_bf16(A1, B1, oacc[1][1], 0, 0, 0);
        }
    }

    // epilogue: add sum_e wts[e][tok]*b2[e][o], store
#pragma unroll
    for (int n = 0; n < 2; ++n) {
        int o = gn * 64 + n * 32 + l31;
        float b2v[EE];
#pragma unroll
        for (int e = 0; e < EE; ++e) b2v[e] = b2[e * OO + o];
#pragma unroll
        for (int m = 0; m < 2; ++m) {
#pragma unroll
            for (int r = 0; r < 16; ++r) {
                int tok = gm * 64 + m * 32 + (r & 3) + 8 * (r >> 2) + 4 * lg2;
                float wb = 0.f;
#pragma unroll
                for (int e = 0; e < EE; ++e) wb += wts[e * 128 + tok] * b2v[e];
                out[(size_t)(t0 + tok) * OO + o] = oacc[m][n][r] + wb;
            }
        }
    }
}

extern "C" void kernel_launch(void* const* d_in, const int* in_sizes, int n_in,
                              void* d_out, int out_size, void* d_ws, size_t ws_size,
                              hipStream_t stream) {
    const float* x  = (const float*)d_in[0];
    const float* gw = (const float*)d_in[1];
    const float* gb = (const float*)d_in[2];
    const float* w1 = (const float*)d_in[3];
    const float* b1 = (const float*)d_in[4];
    const float* w2 = (const float*)d_in[5];
    const float* b2 = (const float*)d_in[6];
    float* out = (float*)d_out;

    char* ws = (char*)d_ws;
    u16* w1t    = (u16*)(ws);                    // 2 MB
    u16* w2t    = (u16*)(ws + 2097152);          // 2 MB
    float* wt   = (float*)(ws + 4194304);        // 2 MB ([E][T])
    double* prt = (double*)(ws + 6291456);       // 2 KB

    k_conv_w1<<<(EE * HH * DD) / 256, 256, 0, stream>>>(w1, w1t);
    k_conv_w2<<<(EE * OO * HH) / 256, 256, 0, stream>>>(w2, w2t);
    k_gating<<<TT / 256, 256, 0, stream>>>(x, gw, gb, wt, prt);
    k_moe<<<TT / 128, 512, 0, stream>>>(x, w1t, w2t, b1, b2, wt, out);
    k_final<<<1, 256, 0, stream>>>(prt, out + (size_t)TT * OO);
}

// Round 6
// 687.204 us; speedup vs baseline: 1.0366x; 1.0366x over previous
//
#include <hip/hip_runtime.h>
#include <math.h>

#define TT 65536
#define DD 256
#define EE 8
#define HH 512
#define OO 256

typedef unsigned int u32;
typedef unsigned short u16;
typedef __attribute__((ext_vector_type(4))) float f32x4;
typedef __attribute__((ext_vector_type(16))) float f32x16;
typedef __attribute__((ext_vector_type(2))) u32 u32x2;
typedef __attribute__((ext_vector_type(4))) u32 u32x4;
typedef __attribute__((ext_vector_type(8))) __bf16 bf16x8;

__device__ __forceinline__ u16 f2bf(float f) {
    u32 u = __builtin_bit_cast(u32, f);
    u32 r = (u + 0x7fffu + ((u >> 16) & 1u)) >> 16;
    return (u16)r;
}

// packed f32 pair -> 2x bf16 in one VALU op (T12; no builtin on gfx950)
__device__ __forceinline__ u32 cvt_pk_bf16(float lo, float hi) {
    u32 r;
    asm("v_cvt_pk_bf16_f32 %0, %1, %2" : "=v"(r) : "v"(lo), "v"(hi));
    return r;
}

__device__ __forceinline__ bf16x8 ld_frag(const void* p) {
    u32x4 v = *(const u32x4*)p;
    return __builtin_bit_cast(bf16x8, v);
}

// tanh-form gelu via exp2 + rcp
__device__ __forceinline__ float gelu_fast(float v) {
    float t = v * v;
    float u = __builtin_fmaf(t, -0.1029479f, -2.3022075f);
    float z = v * u;
    float e = __builtin_amdgcn_exp2f(z);
    return v * __builtin_amdgcn_rcpf(1.0f + e);
}

// ---------------- convert/transpose weights ----------------
__global__ __launch_bounds__(256) void k_conv_w1(const float* __restrict__ w1, u16* __restrict__ w1t) {
    int i = blockIdx.x * 256 + threadIdx.x;            // < E*H*D = 1M
    int d = i & 255, h = (i >> 8) & 511, e = i >> 17;
    w1t[i] = f2bf(w1[((size_t)e << 17) + ((size_t)d << 9) + h]);
}
__global__ __launch_bounds__(256) void k_conv_w2(const float* __restrict__ w2, u16* __restrict__ w2t) {
    int i = blockIdx.x * 256 + threadIdx.x;            // < E*O*H = 1M
    int h = i & 511, o = (i >> 9) & 255, e = i >> 17;
    w2t[i] = f2bf(w2[((size_t)e << 17) + ((size_t)h << 8) + o]);
}

// ---------------- gating ----------------
__global__ __launch_bounds__(256) void k_gating(const float* __restrict__ x,
                                                const float* __restrict__ gw,
                                                const float* __restrict__ gb,
                                                float* __restrict__ wt,
                                                double* __restrict__ part) {
    __shared__ float gws[DD * EE];
    __shared__ float gbs[EE];
    __shared__ double red[256];
    int tid = threadIdx.x;
    for (int i = tid; i < DD * EE; i += 256) gws[i] = gw[i];
    if (tid < EE) gbs[tid] = gb[tid];
    __syncthreads();

    int t = blockIdx.x * 256 + tid;
    double l[EE];
#pragma unroll
    for (int e = 0; e < EE; ++e) l[e] = (double)gbs[e];

    const f32x4* xr = (const f32x4*)(x + (size_t)t * DD);
    for (int d4 = 0; d4 < DD / 4; ++d4) {
        f32x4 xv = xr[d4];
#pragma unroll
        for (int j = 0; j < 4; ++j) {
            double xs = (double)xv[j];
            int d = d4 * 4 + j;
#pragma unroll
            for (int e = 0; e < EE; ++e) l[e] += xs * (double)gws[d * EE + e];
        }
    }
    double mx = l[0];
#pragma unroll
    for (int e = 1; e < EE; ++e) mx = l[e] > mx ? l[e] : mx;
    double p[EE], s = 0.0;
#pragma unroll
    for (int e = 0; e < EE; ++e) { p[e] = exp(l[e] - mx); s += p[e]; }
    double inv = 1.0 / s;
    double ent = 0.0;
#pragma unroll
    for (int e = 0; e < EE; ++e) { p[e] *= inv; ent += p[e] * log(p[e] + 1e-8); }

    bool mask[EE];
#pragma unroll
    for (int e = 0; e < EE; ++e) {
        double c = 0.0; int rk = 0;
#pragma unroll
        for (int f = 0; f < EE; ++f) {
            bool before = (p[f] > p[e]) || (p[f] == p[e] && f < e);
            if (before) { c += p[f]; rk++; }
        }
        c += p[e];
        mask[e] = (c <= 0.7) || (rk == 0);
    }
    double ms = 0.0;
#pragma unroll
    for (int e = 0; e < EE; ++e) if (mask[e]) ms += p[e];
    double inv2 = 1.0 / ms;
#pragma unroll
    for (int e = 0; e < EE; ++e) wt[(size_t)e * TT + t] = (float)(mask[e] ? p[e] * inv2 : 0.0);

    red[tid] = -ent;
    __syncthreads();
    for (int st = 128; st > 0; st >>= 1) {
        if (tid < st) red[tid] += red[tid + st];
        __syncthreads();
    }
    if (tid == 0) part[blockIdx.x] = red[0];
}

__global__ __launch_bounds__(256) void k_final(const double* __restrict__ part, float* __restrict__ loss) {
    __shared__ double red[256];
    int tid = threadIdx.x;
    red[tid] = part[tid];
    __syncthreads();
    for (int st = 128; st > 0; st >>= 1) {
        if (tid < st) red[tid] += red[tid + st];
        __syncthreads();
    }
    if (tid == 0) loss[0] = (float)(red[0] / (double)TT);
}

// ---------------- fused MoE MLP (v6: 128 tok/block, 2:1 MFMA:LDS, no reg cap) ----------------
// 128 tokens/block, 512 threads (8 waves). 16 chunks of 256 h (e = c>>1).
// G1: wave = 64h x 64tok (2x2 tiles): per ks 2 global A + 2 LDS B -> 4 MFMA.
// G2: wave = 64tok x 64o (2x2 tiles): per ks 2 LDS A + 2 global B -> 4 MFMA.
// LDS = 64K Xs + 64K Hs + 4K wts = 132K -> 1 block/CU, 8 waves (2/SIMD).
__global__ __launch_bounds__(512, 1) void k_moe(const float* __restrict__ x,
                                                const u16* __restrict__ w1t,
                                                const u16* __restrict__ w2t,
                                                const float* __restrict__ b1,
                                                const float* __restrict__ b2,
                                                const float* __restrict__ wtg,
                                                float* __restrict__ out) {
    __shared__ __align__(16) unsigned char smem[135168];
    unsigned char* Xs = smem;                     // 128 rows x 512B (bf16, swizzled)
    unsigned char* Hs = smem + 65536;             // 128 rows x 512B (bf16, swizzled)
    float* wts = (float*)(smem + 131072);         // [E][128] f32

    const int tid = threadIdx.x;                  // 0..511
    const int wid = tid >> 6;                     // 0..7
    const int lane = tid & 63;
    const int l31 = lane & 31;
    const int lg2 = lane >> 5;                    // 0..1
    const int gm = wid & 1;                       // token-group (64 tokens)
    const int gh = wid >> 1;                      // G1: 64-h strip within 256-chunk
    const int gn = wid >> 1;                      // G2: 64-o strip within 256
    const int t0 = blockIdx.x * 128;

    // stage X tile: f32 -> bf16, swizzle ^((row&15)<<4), rows = 512B
    {
        const f32x4* xsrc = (const f32x4*)(x + (size_t)t0 * DD);
#pragma unroll
        for (int i = 0; i < 8; ++i) {
            int L = i * 8192 + tid * 16;          // byte offset in 128KB bf16 tile
            f32x4 a = xsrc[L >> 3];
            f32x4 b = xsrc[(L >> 3) + 1];
            u32x4 o;
            o.x = cvt_pk_bf16(a[0], a[1]);
            o.y = cvt_pk_bf16(a[2], a[3]);
            o.z = cvt_pk_bf16(b[0], b[1]);
            o.w = cvt_pk_bf16(b[2], b[3]);
            int row = L >> 9;
            *(u32x4*)(Xs + (L ^ ((row & 15) << 4))) = o;
        }
    }
    // wts[e][tok]
    {
        int i0 = tid;
        wts[i0] = wtg[(size_t)(i0 >> 7) * TT + t0 + (i0 & 127)];
        int i1 = tid + 512;
        wts[i1] = wtg[(size_t)(i1 >> 7) * TT + t0 + (i1 & 127)];
    }
    __syncthreads();

    f32x16 oacc[2][2];
#pragma unroll
    for (int m = 0; m < 2; ++m)
#pragma unroll
        for (int n = 0; n < 2; ++n) oacc[m][n] = (f32x16)0.0f;

#pragma unroll 1
    for (int c = 0; c < 16; ++c) {
        const int e = c >> 1;
        // ---- G1: hf[m][t], rows h = c*256 + gh*64 + m*32 + crow, cols tok = gm*64 + t*32 + l31
        f32x16 hf[2][2];
#pragma unroll
        for (int m = 0; m < 2; ++m)
#pragma unroll
            for (int t = 0; t < 2; ++t) hf[m][t] = (f32x16)0.0f;

        const u16* w1p = w1t + ((size_t)(c * 256 + gh * 64 + l31)) * DD + lg2 * 8;
        const int xb0 = (gm * 64 + l31) * 512 + lg2 * 16;
        const int xs0 = ((gm * 64 + l31) & 15) << 4;
        const int xb1 = (gm * 64 + 32 + l31) * 512 + lg2 * 16;
        const int xs1 = ((gm * 64 + 32 + l31) & 15) << 4;
#pragma unroll
        for (int ks = 0; ks < 16; ++ks) {
            bf16x8 a0 = ld_frag(w1p + ks * 16);
            bf16x8 a1 = ld_frag(w1p + 32 * DD + ks * 16);
            bf16x8 b0 = ld_frag(Xs + ((xb0 + ks * 32) ^ xs0));
            bf16x8 b1f = ld_frag(Xs + ((xb1 + ks * 32) ^ xs1));
            hf[0][0] = __builtin_amdgcn_mfma_f32_32x32x16_bf16(a0, b0, hf[0][0], 0, 0, 0);
            hf[0][1] = __builtin_amdgcn_mfma_f32_32x32x16_bf16(a0, b1f, hf[0][1], 0, 0, 0);
            hf[1][0] = __builtin_amdgcn_mfma_f32_32x32x16_bf16(a1, b0, hf[1][0], 0, 0, 0);
            hf[1][1] = __builtin_amdgcn_mfma_f32_32x32x16_bf16(a1, b1f, hf[1][1], 0, 0, 0);
        }
        __syncthreads();               // all waves done reading Hs for G2(c-1)
        // epilogue: +b1, gelu, *wgt, pack -> Hs
#pragma unroll
        for (int m = 0; m < 2; ++m) {
            f32x4 bbv[4];
            const float* b1p = b1 + c * 256 + gh * 64 + m * 32 + lg2 * 4;
#pragma unroll
            for (int q = 0; q < 4; ++q) bbv[q] = *(const f32x4*)(b1p + q * 8);
#pragma unroll
            for (int t = 0; t < 2; ++t) {
                int tok = gm * 64 + t * 32 + l31;
                float wgt = wts[e * 128 + tok];
#pragma unroll
                for (int q = 0; q < 4; ++q) {
                    float g[4];
#pragma unroll
                    for (int r = 0; r < 4; ++r) {
                        float v = hf[m][t][q * 4 + r] + bbv[q][r];
                        g[r] = gelu_fast(v) * wgt;
                    }
                    u32x2 pk;
                    pk.x = cvt_pk_bf16(g[0], g[1]);
                    pk.y = cvt_pk_bf16(g[2], g[3]);
                    int hl = gh * 64 + m * 32 + q * 8 + lg2 * 4;   // h within chunk [0,256)
                    int byt = tok * 512 + hl * 2;
                    *(u32x2*)(Hs + (byt ^ ((tok & 15) << 4))) = pk;
                }
            }
        }
        __syncthreads();               // Hs(c) ready
        // ---- G2: oacc[m][n] += Hs[tok][k] * W2[k][o]
        const u16* w2p = w2t + ((size_t)(e * OO + gn * 64 + l31)) * HH + (c & 1) * 256 + lg2 * 8;
#pragma unroll
        for (int ks = 0; ks < 16; ++ks) {
            bf16x8 A0 = ld_frag(Hs + ((xb0 + ks * 32) ^ xs0));
            bf16x8 A1 = ld_frag(Hs + ((xb1 + ks * 32) ^ xs1));
            bf16x8 B0 = ld_frag(w2p + ks * 16);
            bf16x8 B1 = ld_frag(w2p + 32 * HH + ks * 16);
            oacc[0][0] = __builtin_amdgcn_mfma_f32_32x32x16_bf16(A0, B0, oacc[0][0], 0, 0, 0);
            oacc[0][1] = __builtin_amdgcn_mfma_f32_32x32x16_bf16(A0, B1, oacc[0][1], 0, 0, 0);
            oacc[1][0] = __builtin_amdgcn_mfma_f32_32x32x16_bf16(A1, B0, oacc[1][0], 0, 0, 0);
            oacc[1][1] = __builtin_amdgcn_mfma_f32_32x32x16_bf16(A1, B1, oacc[1][1], 0, 0, 0);
        }
    }

    // epilogue: add sum_e wts[e][tok]*b2[e][o], store
#pragma unroll
    for (int n = 0; n < 2; ++n) {
        int o = gn * 64 + n * 32 + l31;
        float b2v[EE];
#pragma unroll
        for (int e = 0; e < EE; ++e) b2v[e] = b2[e * OO + o];
#pragma unroll
        for (int m = 0; m < 2; ++m) {
#pragma unroll
            for (int r = 0; r < 16; ++r) {
                int tok = gm * 64 + m * 32 + (r & 3) + 8 * (r >> 2) + 4 * lg2;
                float wb = 0.f;
#pragma unroll
                for (int e = 0; e < EE; ++e) wb += wts[e * 128 + tok] * b2v[e];
                out[(size_t)(t0 + tok) * OO + o] = oacc[m][n][r] + wb;
            }
        }
    }
}

extern "C" void kernel_launch(void* const* d_in, const int* in_sizes, int n_in,
                              void* d_out, int out_size, void* d_ws, size_t ws_size,
                              hipStream_t stream) {
    const float* x  = (const float*)d_in[0];
    const float* gw = (const float*)d_in[1];
    const float* gb = (const float*)d_in[2];
    const float* w1 = (const float*)d_in[3];
    const float* b1 = (const float*)d_in[4];
    const float* w2 = (const float*)d_in[5];
    const float* b2 = (const float*)d_in[6];
    float* out = (float*)d_out;

    char* ws = (char*)d_ws;
    u16* w1t    = (u16*)(ws);                    // 2 MB
    u16* w2t    = (u16*)(ws + 2097152);          // 2 MB
    float* wt   = (float*)(ws + 4194304);        // 2 MB ([E][T])
    double* prt = (double*)(ws + 6291456);       // 2 KB

    k_conv_w1<<<(EE * HH * DD) / 256, 256, 0, stream>>>(w1, w1t);
    k_conv_w2<<<(EE * OO * HH) / 256, 256, 0, stream>>>(w2, w2t);
    k_gating<<<TT / 256, 256, 0, stream>>>(x, gw, gb, wt, prt);
    k_moe<<<TT / 128, 512, 0, stream>>>(x, w1t, w2t, b1, b2, wt, out);
    k_final<<<1, 256, 0, stream>>>(prt, out + (size_t)TT * OO);
}